// Round 1
// baseline (153.228 us; speedup 1.0000x reference)
//
#include <hip/hip_runtime.h>

// VQ-VAE quantizer, MI355X (gfx950). B=64, C=D=64, H=32, W=32 -> N=65536 tokens, K=1024 codes.
// Round 5: attack the L2-BW-bound main loop.
//   Theory: R4's 32-tokens/wave loop pulls 4KB B-frags/chunk/wave from L2 = 512 MB total
//   (~53 B/cyc/CU ~= the ~56 B/cyc/CU per-CU L2 ceiling) -> queuing latency + per-chunk
//   vmcnt(0) on the 1-deep prefetch = the ~50% stall (MfmaUtil 21, VALUBusy 27, HBM 6%).
//   Fix: 64 tokens/wave (4 A-groups) halves L2 codebook traffic per MFMA (512->256 MB)
//   and doubles per-chunk compute (32 MFMA) over the same prefetch -> 2x latency slack.
//   512 blocks x 256 thr, launch_bounds(256,2): ~150 VGPR ok, 2 waves/SIMD, barrier-free loop.
//   Also: finalize folded into vq via last-block pattern (saves 1 dispatch + gap).
//   Score arithmetic is bit-identical to R4 (same MFMA order/ini/merge ties) -> same argmin.
// Outputs (flat): z_q [4194304] f32 NCHW, loss [1], perplexity [1].

typedef __attribute__((ext_vector_type(8))) short short8;   // 8 bf16 (4 VGPRs)
typedef __attribute__((ext_vector_type(4))) float float4v;  // MFMA C/D frag

#define NELEM 4194304
#define NBLK  512        // vq grid

// ---- workspace layout (bytes) ----
#define WS_CBF   0        // ushort[131072]: packed split-bf16 codebook, B-frag order (256 KB)
#define WS_C2H   262144   // f32 c2h[1024] = -0.5*||c||^2
#define WS_HIST  266240   // i32 hist[1024]
#define WS_LOSS  270336   // f32 loss_part[32]
#define WS_DONE  270464   // i32 done-counter (fits inside R4's 270592-byte footprint)

__device__ __forceinline__ unsigned bf16_rne(float x) {
    unsigned u = __float_as_uint(x);
    return (u + 0x7fffu + ((u >> 16) & 1u)) >> 16;
}

// grid = 68 blocks x 256. Blocks 0..63: pack chunk bx (thread (fid=wave, lane) -> one
// contiguous 16B fragment) + c2. Blocks 64..67: zero hist; block 64 zeroes loss_part+done.
// Fragment layout: cbf[((chunk*4 + fid)*64 + lane)*8 + j], fid = split*2 + st,
// lane = kq*16 + col, code = chunk*16+col, dims d = st*32 + kq*8 + j.
__global__ __launch_bounds__(256) void prep_kernel(
    const float* __restrict__ cb, ushort* __restrict__ cbf,
    float* __restrict__ c2h, int* __restrict__ hist, float* __restrict__ loss_part,
    int* __restrict__ done) {
    __shared__ float s_c2[2][16];
    int tid  = threadIdx.x;
    int lane = tid & 63, wave = tid >> 6;
    int quad = lane >> 4, col = lane & 15;
    int bx   = blockIdx.x;

    if (bx >= 64) {
        hist[(bx - 64) * 256 + tid] = 0;
        if (bx == 64) {
            if (tid < 32)  loss_part[tid] = 0.f;
            if (tid == 32) *done = 0;
        }
        return;
    }
    int c = bx, fid = wave;
    int st = fid & 1, split = fid >> 1;
    int code  = c * 16 + col;
    int dbase = st * 32 + quad * 8;
    const float* cp = cb + code * 64 + dbase;
    float4v v0 = *(const float4v*)cp;
    float4v v1 = *(const float4v*)(cp + 4);
    float xs[8] = {v0.x, v0.y, v0.z, v0.w, v1.x, v1.y, v1.z, v1.w};
    short8 frag;
    float ssq = 0.f;
#pragma unroll
    for (int j = 0; j < 8; j++) {
        float x = xs[j];
        ssq = fmaf(x, x, ssq);
        unsigned hb = bf16_rne(x);
        if (split == 0) frag[j] = (short)hb;
        else            frag[j] = (short)bf16_rne(x - __uint_as_float(hb << 16));
    }
    *(short8*)(cbf + ((c * 4 + fid) * 64 + lane) * 8) = frag;   // contiguous 16B store
    if (split == 0) {                    // c2 from exact f32, deterministic order
        ssq += __shfl_xor(ssq, 16);      // sum over kq (lane bits 4..5)
        ssq += __shfl_xor(ssq, 32);
        if (quad == 0) s_c2[st][col] = ssq;
    }
    __syncthreads();
    if (tid < 16) c2h[c * 16 + tid] = -0.5f * (s_c2[0][tid] + s_c2[1][tid]);
}

// grid = 512 blocks x 256 (4 waves, 2 blocks/CU, 2 waves/SIMD). Block = 128 tokens.
// wave: tokgrp = wave&1 (64 tokens = 4 groups of 16), khalf = wave>>1 (chunks khalf*32..+31).
__global__ __launch_bounds__(256, 2) void vq_kernel(
    const float* __restrict__ z, const float* __restrict__ cb,
    const ushort* __restrict__ cbf, const float* __restrict__ c2h,
    float* __restrict__ out, float* __restrict__ loss_part, int* __restrict__ hist,
    int* __restrict__ done, const int* __restrict__ flg)
{
    __shared__ float s_q[128 * 65];      // gathered code rows, +1 pad (33.3 KB)
    __shared__ float s_ms[2][128];       // K-half merge: score
    __shared__ int   s_mi[2][128];       // K-half merge: index
    __shared__ int   s_idx[128];
    __shared__ float s_red[4];
    __shared__ int   s_last;

    int tid  = threadIdx.x;
    int lane = tid & 63, wave = tid >> 6;
    int quad = lane >> 4, col = lane & 15;
    int bx   = blockIdx.x;

    int tokbase = bx * 128;
    int bb = tokbase >> 10, hwb = tokbase & 1023;
    const float* zb = z + bb * 65536 + hwb;
    int tokgrp = wave & 1, khalf = wave >> 1;

    // A-fragments: 4 groups x {hi,lo} x 2 K-steps, loaded once (64 VGPRs)
    short8 ah[4][2], al[4][2];
#pragma unroll
    for (int g = 0; g < 4; g++) {
        int rel = tokgrp * 64 + g * 16 + col;        // token row m = lane&15
#pragma unroll
        for (int st = 0; st < 2; st++) {
            short8 h8, l8;
#pragma unroll
            for (int j = 0; j < 8; j++) {
                int d = st * 32 + quad * 8 + j;      // k = quad*8+j
                float x = zb[d * 1024 + rel];
                unsigned hb = bf16_rne(x);
                h8[j] = (short)hb;
                l8[j] = (short)bf16_rne(x - __uint_as_float(hb << 16));
            }
            ah[g][st] = h8; al[g][st] = l8;
        }
    }

    float best[4][4]; int bidx[4][4];
#pragma unroll
    for (int g = 0; g < 4; g++)
#pragma unroll
        for (int r = 0; r < 4; r++) { best[g][r] = -1e38f; bidx[g][r] = 0; }

    // k-loop: 32 chunks, register double-buffered B-frag prefetch, no barriers.
    // Per chunk: 4 KB from L2, 32 MFMA (2x the work per byte vs R4).
    int cbase = khalf * 32;
    const ushort* cw = cbf + lane * 8;
    {
        const ushort* p0 = cw + cbase * 2048;
        short8 nb0 = *(const short8*)(p0 + 0);
        short8 nb1 = *(const short8*)(p0 + 512);
        short8 nb2 = *(const short8*)(p0 + 1024);
        short8 nb3 = *(const short8*)(p0 + 1536);
        float  nini = c2h[cbase * 16 + col];
        for (int cc = 0; cc < 32; cc++) {
            short8 bh0 = nb0, bh1 = nb1, bl0 = nb2, bl1 = nb3;
            float  ini = nini;
            if (cc < 31) {                            // prefetch next chunk
                const ushort* np = cw + (cbase + cc + 1) * 2048;
                nb0 = *(const short8*)(np + 0);
                nb1 = *(const short8*)(np + 512);
                nb2 = *(const short8*)(np + 1024);
                nb3 = *(const short8*)(np + 1536);
                nini = c2h[(cbase + cc + 1) * 16 + col];
            }
            int code = (cbase + cc) * 16 + col;
#pragma unroll
            for (int g = 0; g < 4; g++) {
                float4v a0 = {ini, ini, ini, ini};    // score = dot - c2/2 (argmax)
                float4v a1 = {0.f, 0.f, 0.f, 0.f};
                a0 = __builtin_amdgcn_mfma_f32_16x16x32_bf16(ah[g][0], bh0, a0, 0, 0, 0);
                a1 = __builtin_amdgcn_mfma_f32_16x16x32_bf16(ah[g][1], bh1, a1, 0, 0, 0);
                a0 = __builtin_amdgcn_mfma_f32_16x16x32_bf16(ah[g][0], bl0, a0, 0, 0, 0);
                a1 = __builtin_amdgcn_mfma_f32_16x16x32_bf16(ah[g][1], bl1, a1, 0, 0, 0);
                a0 = __builtin_amdgcn_mfma_f32_16x16x32_bf16(al[g][0], bh0, a0, 0, 0, 0);
                a1 = __builtin_amdgcn_mfma_f32_16x16x32_bf16(al[g][1], bh1, a1, 0, 0, 0);
                a0 = __builtin_amdgcn_mfma_f32_16x16x32_bf16(al[g][0], bl0, a0, 0, 0, 0);
                a1 = __builtin_amdgcn_mfma_f32_16x16x32_bf16(al[g][1], bl1, a1, 0, 0, 0);
#pragma unroll
                for (int r = 0; r < 4; r++) {
                    float s = a0[r] + a1[r];
                    if (s > best[g][r]) { best[g][r] = s; bidx[g][r] = code; }  // strict >: first-min
                }
            }
        }
    }

    // quad-reduction (C row = quad*4+r = token, col = code lane)
#pragma unroll
    for (int g = 0; g < 4; g++) {
#pragma unroll
        for (int r = 0; r < 4; r++) {
            float s = best[g][r]; int ix = bidx[g][r];
#pragma unroll
            for (int m = 1; m <= 8; m <<= 1) {
                float so = __shfl_xor(s, m);
                int   io = __shfl_xor(ix, m);
                if (so > s || (so == s && io < ix)) { s = so; ix = io; }
            }
            if (col == 0) {
                int t = tokgrp * 64 + g * 16 + quad * 4 + r;
                s_ms[khalf][t] = s; s_mi[khalf][t] = ix;
            }
        }
    }
    __syncthreads();

    // merge K-halves (half0 codes < half1 codes: tie -> half0 = first-min)
    if (tid < 128) {
        float s0 = s_ms[0][tid], s1 = s_ms[1][tid];
        int   i0 = s_mi[0][tid], i1 = s_mi[1][tid];
        int   ix = (s1 > s0) ? i1 : i0;
        s_idx[tid] = ix;
        atomicAdd(&hist[ix], 1);                       // one per token
    }
    __syncthreads();

    // gather selected code rows (wave-uniform row, 256B coalesced)
#pragma unroll 8
    for (int p = 0; p < 32; p++) {
        int i = p * 256 + tid;
        int t = i >> 6, d = i & 63;
        s_q[t * 65 + d] = cb[s_idx[t] * 64 + d];
    }
    __syncthreads();

    // straight-through output + loss (coalesced along tokens per d)
    float ls = 0.f;
#pragma unroll 4
    for (int p = 0; p < 32; p++) {
        int i = p * 256 + tid;
        int d = i >> 7, t = i & 127;
        int a = d * 1024 + t;
        float zv = zb[a];
        float q  = s_q[t * 65 + d];                    // bank(t*65+d): conflict-free
        float df = q - zv;
        out[bb * 65536 + hwb + a] = zv + df;           // z + (z_q - z)
        ls = fmaf(df, df, ls);
    }
#pragma unroll
    for (int off = 32; off; off >>= 1) ls += __shfl_down(ls, off);
    if (lane == 0) s_red[wave] = ls;
    __syncthreads();
    if (tid == 0) {
        float v = (s_red[0] + s_red[1]) + (s_red[2] + s_red[3]);
        atomicAdd(&loss_part[bx & 31], v);
        __threadfence();                               // release all prior hist/loss atomics
        int old = __hip_atomic_fetch_add(done, 1, __ATOMIC_ACQ_REL, __HIP_MEMORY_SCOPE_AGENT);
        s_last = (old == NBLK - 1) ? 1 : 0;
    }
    __syncthreads();

    // last block: finalize (perplexity + loss) -- replaces the 3rd dispatch
    if (s_last) {
        float v = 0.f;
#pragma unroll
        for (int rr = 0; rr < 4; rr++) {
            int k = rr * 256 + tid;
            float e = (float)__hip_atomic_load(&hist[k], __ATOMIC_RELAXED,
                                               __HIP_MEMORY_SCOPE_AGENT) * (1.0f / 65536.0f);
            v += e * logf(e + 1e-10f);
        }
#pragma unroll
        for (int off = 32; off; off >>= 1) v += __shfl_down(v, off);
        if (lane == 0) s_red[wave] = v;
        float lsum = 0.f;
        if (tid < 32) lsum = __hip_atomic_load(&loss_part[tid], __ATOMIC_RELAXED,
                                               __HIP_MEMORY_SCOPE_AGENT);
#pragma unroll
        for (int off = 16; off; off >>= 1) lsum += __shfl_down(lsum, off);
        __syncthreads();
        if (tid == 0) {
            float sE = (s_red[0] + s_red[1]) + (s_red[2] + s_red[3]);
            out[NELEM + 1] = expf(-sE);                // perplexity
            float m = lsum * (1.0f / (float)NELEM);
            out[NELEM] = (*flg) ? (0.25f * m + m) : 0.0f;  // BETA*mean + mean
        }
    }
}

extern "C" void kernel_launch(void* const* d_in, const int* in_sizes, int n_in,
                              void* d_out, int out_size, void* d_ws, size_t ws_size,
                              hipStream_t stream) {
    const float* z   = (const float*)d_in[0];   // (64,64,32,32) f32 NCHW
    const float* cb  = (const float*)d_in[1];   // (1024,64) f32
    const int*   flg = (const int*)d_in[3];     // flg_train

    float* out = (float*)d_out;
    char*  ws  = (char*)d_ws;

    ushort* cbf       = (ushort*)(ws + WS_CBF);
    float*  c2h       = (float*)(ws + WS_C2H);
    int*    hist      = (int*)(ws + WS_HIST);
    float*  loss_part = (float*)(ws + WS_LOSS);
    int*    done      = (int*)(ws + WS_DONE);

    prep_kernel<<<68, 256, 0, stream>>>(cb, cbf, c2h, hist, loss_part, done);
    vq_kernel<<<NBLK, 256, 0, stream>>>(z, cb, cbf, c2h, out, loss_part, hist, done, flg);
}